// Round 9
// baseline (533.819 us; speedup 1.0000x reference)
//
#include <hip/hip_runtime.h>
#include <hip/hip_bf16.h>

// ---------------------------------------------------------------------------
// NextTaskGAT: 2-layer GAT (H=4, C=64, F_IN=256) + FC(256->64).
// PINNED dtype model: inputs fp32 (bf16-grid), edge_index int32, dict order,
// OUTPUT FP32 (reference returns float32 — the r2-r8 bug was writing bf16).
// Fast pipeline: MFMA GEMMs (bf16 in, proven r4≡r6≡r7≡r8), CSR gather.
// ---------------------------------------------------------------------------

#define HEADS 4
#define FDIM  256

typedef __attribute__((ext_vector_type(4))) float f32x4;
typedef __attribute__((ext_vector_type(8))) short s16x8;

__device__ __forceinline__ void gload_lds16(const void* g, void* l) {
    __builtin_amdgcn_global_load_lds(
        (__attribute__((address_space(1))) void*)g,
        (__attribute__((address_space(3))) void*)l, 16, 0, 0);
}

__device__ __forceinline__ float b2f(unsigned short u) {
    return __uint_as_float((unsigned)u << 16);
}
__device__ __forceinline__ unsigned short f2b(float f) {
    __hip_bfloat16 b = __float2bfloat16(f);
    return *(unsigned short*)&b;
}

// ---------------------------------------------------------------------------
// Conversions: x fp32 -> bf16; W fp32 [K][N] -> bf16 transposed [N][K].
// ---------------------------------------------------------------------------
__global__ void cvt_x_bf16(const float* __restrict__ in,
                           unsigned short* __restrict__ out, int count) {
    int i = blockIdx.x * 256 + threadIdx.x;
    if (i < count) out[i] = f2b(in[i]);
}

__global__ void cvt_w_t(const float* __restrict__ in,
                        unsigned short* __restrict__ out, int rows, int cols) {
    int i = blockIdx.x * 256 + threadIdx.x;
    if (i >= rows * cols) return;
    int r = i / cols, c = i % cols;
    out[c * rows + r] = f2b(in[i]);
}

// ---------------------------------------------------------------------------
// GEMM: C[M][ncol] = A[M][256](bf16) x Bt[ncol][256]^T(bf16), +fp32 bias.
// BM=128, BK=64, 4 waves 2x2, XOR-swizzled 16B groups, global_load_lds.
// F32OUT: write float (final FC into d_out) else bf16 ushort.
// ---------------------------------------------------------------------------
template <int BN, bool F32OUT>
__global__ __launch_bounds__(256, 2)
void gemm_bt_k256(const unsigned short* __restrict__ A,
                  const unsigned short* __restrict__ Bt,
                  void* __restrict__ C,
                  const float* __restrict__ bias,
                  int M, int ncol) {
    constexpr int BM = 128, BK = 64;
    constexpr int NFRAG = BN / 32;
    __shared__ __align__(16) unsigned short lA[BM * BK];
    __shared__ __align__(16) unsigned short lB[BN * BK];

    const int tid  = threadIdx.x;
    const int lane = tid & 63;
    const int wave = tid >> 6;
    const int wm = wave & 1, wn = wave >> 1;
    const int m0 = blockIdx.x * BM;
    const int n0 = blockIdx.y * BN;
    const int quad = lane >> 4, col16 = lane & 15;

    f32x4 acc[4][NFRAG];
#pragma unroll
    for (int i = 0; i < 4; ++i)
#pragma unroll
        for (int j = 0; j < NFRAG; ++j) acc[i][j] = (f32x4){0.f, 0.f, 0.f, 0.f};

#pragma unroll 1
    for (int kt = 0; kt < 4; ++kt) {
        const int k0 = kt * BK;
#pragma unroll
        for (int i = 0; i < 4; ++i) {
            int slot = tid + i * 256;
            int row = slot >> 3, g = slot & 7;
            int gs = g ^ (row & 7);
            int rg = m0 + row; rg = rg < M ? rg : (M - 1);
            gload_lds16(A + (size_t)rg * FDIM + k0 + gs * 8,
                        (char*)lA + (size_t)slot * 16);
        }
#pragma unroll
        for (int i = 0; i < BN * 8 / 256; ++i) {
            int slot = tid + i * 256;
            int row = slot >> 3, g = slot & 7;
            int gs = g ^ (row & 7);
            gload_lds16(Bt + (size_t)(n0 + row) * FDIM + k0 + gs * 8,
                        (char*)lB + (size_t)slot * 16);
        }
        __syncthreads();

#pragma unroll
        for (int kk = 0; kk < 2; ++kk) {
            const int kg = kk * 4 + quad;
            s16x8 af[4], bfr[NFRAG];
#pragma unroll
            for (int i = 0; i < 4; ++i) {
                int row = wm * 64 + i * 16 + col16;
                int g = kg ^ (row & 7);
                af[i] = *(const s16x8*)((const char*)lA + (size_t)(row * 8 + g) * 16);
            }
#pragma unroll
            for (int j = 0; j < NFRAG; ++j) {
                int row = wn * (BN / 2) + j * 16 + col16;
                int g = kg ^ (row & 7);
                bfr[j] = *(const s16x8*)((const char*)lB + (size_t)(row * 8 + g) * 16);
            }
#pragma unroll
            for (int i = 0; i < 4; ++i)
#pragma unroll
                for (int j = 0; j < NFRAG; ++j)
                    acc[i][j] = __builtin_amdgcn_mfma_f32_16x16x32_bf16(
                        af[i], bfr[j], acc[i][j], 0, 0, 0);
        }
        __syncthreads();
    }

    // epilogue: D row = quad*4 + r, col = lane&15 (m89-verified layout)
#pragma unroll
    for (int i = 0; i < 4; ++i) {
#pragma unroll
        for (int j = 0; j < NFRAG; ++j) {
#pragma unroll
            for (int r = 0; r < 4; ++r) {
                int row = m0 + wm * 64 + i * 16 + quad * 4 + r;
                int col = n0 + wn * (BN / 2) + j * 16 + col16;
                if (row < M) {
                    float v = acc[i][j][r];
                    if (bias) v += bias[col];
                    if constexpr (F32OUT)
                        ((float*)C)[(size_t)row * ncol + col] = v;
                    else
                        ((unsigned short*)C)[(size_t)row * ncol + col] = f2b(v);
                }
            }
        }
    }
}

// ---------------------------------------------------------------------------
// Attention coefficients: one wave per node; h bf16, a-vectors fp32 direct.
// lane covers flat channels 4*lane..4*lane+3; head = lane/16.
// ---------------------------------------------------------------------------
__global__ void att_coef(const unsigned short* __restrict__ h,
                         const float* __restrict__ a_src,
                         const float* __restrict__ a_dst,
                         float* __restrict__ als, float* __restrict__ ald,
                         int n) {
    const int lane = threadIdx.x & 63;
    const int wv = (blockIdx.x * blockDim.x + threadIdx.x) >> 6;
    if (wv >= n) return;
    float4 as = *(const float4*)(a_src + 4 * lane);
    float4 ad = *(const float4*)(a_dst + 4 * lane);

    ushort4 hv = *(const ushort4*)(h + (size_t)wv * FDIM + lane * 4);
    float h0 = b2f(hv.x), h1 = b2f(hv.y), h2 = b2f(hv.z), h3 = b2f(hv.w);
    float vs = h0 * as.x + h1 * as.y + h2 * as.z + h3 * as.w;
    float vd = h0 * ad.x + h1 * ad.y + h2 * ad.z + h3 * ad.w;
#pragma unroll
    for (int off = 1; off < 16; off <<= 1) {
        vs += __shfl_xor(vs, off, 16);
        vd += __shfl_xor(vd, off, 16);
    }
    if ((lane & 15) == 0) {
        als[wv * HEADS + (lane >> 4)] = vs;
        ald[wv * HEADS + (lane >> 4)] = vd;
    }
}

// ---------------------------------------------------------------------------
// CSR build: degree histogram -> exclusive scan -> scatter (src ids by dst)
// ---------------------------------------------------------------------------
__global__ void deg_count(const int* __restrict__ dst, int* __restrict__ deg,
                          int E, int n) {
    int e = blockIdx.x * 256 + threadIdx.x;
    if (e >= E + n) return;
    int d = (e < E) ? dst[e] : (e - E);
    atomicAdd(&deg[d], 1);
}

__global__ __launch_bounds__(1024)
void scan_offsets(const int* __restrict__ deg, int* __restrict__ off,
                  int* __restrict__ cursor, int n) {
    __shared__ int wsum[16];
    __shared__ int carry_s;
    const int tid = threadIdx.x, lane = tid & 63, wv = tid >> 6;
    int carry = 0;
    for (int start = 0; start < n; start += 1024) {
        int i = start + tid;
        int v = (i < n) ? deg[i] : 0;
        int acc = v;
#pragma unroll
        for (int dlt = 1; dlt < 64; dlt <<= 1) {
            int t = __shfl_up(acc, dlt, 64);
            if (lane >= dlt) acc += t;
        }
        if (lane == 63) wsum[wv] = acc;
        __syncthreads();
        if (wv == 0 && lane < 16) {
            int w = wsum[lane];
            int a = w;
#pragma unroll
            for (int dlt = 1; dlt < 16; dlt <<= 1) {
                int t = __shfl_up(a, dlt, 16);
                if (lane >= dlt) a += t;
            }
            wsum[lane] = a - w;   // exclusive prefix of wave totals
        }
        __syncthreads();
        int excl = carry + wsum[wv] + acc - v;
        if (i < n) { off[i] = excl; cursor[i] = excl; }
        if (tid == 1023) carry_s = carry + wsum[15] + acc;
        __syncthreads();
        carry = carry_s;
    }
    if (tid == 0) off[n] = carry;
}

__global__ void scatter_edges(const int* __restrict__ src,
                              const int* __restrict__ dst,
                              int* __restrict__ cursor,
                              int* __restrict__ csr_src, int E, int n) {
    int e = blockIdx.x * 256 + threadIdx.x;
    if (e >= E + n) return;
    int s, d;
    if (e < E) { s = src[e]; d = dst[e]; } else { s = e - E; d = s; }
    int p = atomicAdd(&cursor[d], 1);
    csr_src[p] = s;
}

// ---------------------------------------------------------------------------
// Fused gather: per dst node, inline softmax + weighted sum + bias + ELU.
// One wave per node; lane covers flat channels 4*lane..4*lane+3, head=lane/16.
// ---------------------------------------------------------------------------
__global__ void gat_gather(const int* __restrict__ off,
                           const int* __restrict__ deg,
                           const int* __restrict__ csr_src,
                           const float* __restrict__ als,
                           const float* __restrict__ ald,
                           const unsigned short* __restrict__ h,
                           const float* __restrict__ bias,
                           unsigned short* __restrict__ x2, int n) {
    const int lane = threadIdx.x & 63;
    const int d = (blockIdx.x * blockDim.x + threadIdx.x) >> 6;
    if (d >= n) return;
    const int head = lane >> 4;
    const float aldh = ald[4 * d + head];
    const int start = off[d];
    const int end = start + deg[d];

    float a0 = 0.f, a1 = 0.f, a2 = 0.f, a3 = 0.f, den = 0.f;
    for (int j = start; j < end; ++j) {
        int s = csr_src[j];
        float e = als[4 * s + head] + aldh;
        e = e > 0.f ? e : 0.2f * e;
        float w = __expf(e);
        den += w;
        ushort4 hv = *(const ushort4*)(h + (size_t)s * FDIM + lane * 4);
        a0 += w * b2f(hv.x);
        a1 += w * b2f(hv.y);
        a2 += w * b2f(hv.z);
        a3 += w * b2f(hv.w);
    }
    const float inv = 1.0f / den;
    const int c = lane * 4;
    float v0 = a0 * inv + bias[c + 0];
    float v1 = a1 * inv + bias[c + 1];
    float v2 = a2 * inv + bias[c + 2];
    float v3 = a3 * inv + bias[c + 3];
    v0 = v0 > 0.f ? v0 : expm1f(v0);
    v1 = v1 > 0.f ? v1 : expm1f(v1);
    v2 = v2 > 0.f ? v2 : expm1f(v2);
    v3 = v3 > 0.f ? v3 : expm1f(v3);
    ushort4 o;
    o.x = f2b(v0); o.y = f2b(v1); o.z = f2b(v2); o.w = f2b(v3);
    *(ushort4*)(x2 + (size_t)d * FDIM + c) = o;
}

// ---------------------------------------------------------------------------
extern "C" void kernel_launch(void* const* d_in, const int* in_sizes, int n_in,
                              void* d_out, int out_size, void* d_ws, size_t ws_size,
                              hipStream_t stream) {
    const float* x   = (const float*)d_in[0];
    const int*   ei  = (const int*)d_in[1];
    const float* W1  = (const float*)d_in[3];
    const float* as1 = (const float*)d_in[4];
    const float* ad1 = (const float*)d_in[5];
    const float* b1  = (const float*)d_in[6];
    const float* W2  = (const float*)d_in[7];
    const float* as2 = (const float*)d_in[8];
    const float* ad2 = (const float*)d_in[9];
    const float* b2  = (const float*)d_in[10];
    const float* fcW = (const float*)d_in[11];
    const float* fcb = (const float*)d_in[12];
    float* out = (float*)d_out;        // FP32 output (the r2-r8 bug)

    const int n = in_sizes[0] / FDIM;   // 50000
    const int E = in_sizes[1] / 2;      // 800000
    const int Etot = E + n;
    const int* srcp = ei;
    const int* dstp = ei + E;

    // -------- workspace carve (256B aligned), ~57 MB --------
    char* ws = (char*)d_ws;
    size_t off_b = 0;
    auto carve = [&](size_t bytes) -> char* {
        char* p = ws + off_b;
        off_b += (bytes + 255) & ~(size_t)255;
        return p;
    };
    unsigned short* xb = (unsigned short*)carve((size_t)n * FDIM * 2);  // also x2
    unsigned short* h  = (unsigned short*)carve((size_t)n * FDIM * 2);
    float* als  = (float*)carve((size_t)n * HEADS * 4);
    float* ald  = (float*)carve((size_t)n * HEADS * 4);
    int* deg    = (int*)carve((size_t)n * 4);
    int* offs   = (int*)carve((size_t)(n + 1) * 4);
    int* cursor = (int*)carve((size_t)n * 4);
    int* csr_src = (int*)carve((size_t)Etot * 4);
    unsigned short* Wt1  = (unsigned short*)carve(FDIM * FDIM * 2);
    unsigned short* Wt2  = (unsigned short*)carve(FDIM * FDIM * 2);
    unsigned short* fcWt = (unsigned short*)carve(64 * FDIM * 2);
    unsigned short* x2 = xb;   // alias: xb dead after layer-1 GEMM

    const int mblocks = (n + 127) / 128;

    // -------- conversions (inputs are on the bf16 grid -> lossless) --------
    cvt_x_bf16<<<((size_t)n * FDIM + 255) / 256, 256, 0, stream>>>(x, xb, n * FDIM);
    cvt_w_t<<<(FDIM * FDIM + 255) / 256, 256, 0, stream>>>(W1, Wt1, FDIM, FDIM);
    cvt_w_t<<<(FDIM * FDIM + 255) / 256, 256, 0, stream>>>(W2, Wt2, FDIM, FDIM);
    cvt_w_t<<<(FDIM * 64 + 255) / 256, 256, 0, stream>>>(fcW, fcWt, FDIM, 64);

    // -------- CSR build (graph static across layers) --------
    (void)hipMemsetAsync(deg, 0, (size_t)n * 4, stream);
    deg_count<<<(Etot + 255) / 256, 256, 0, stream>>>(dstp, deg, E, n);
    scan_offsets<<<1, 1024, 0, stream>>>(deg, offs, cursor, n);
    scatter_edges<<<(Etot + 255) / 256, 256, 0, stream>>>(
        srcp, dstp, cursor, csr_src, E, n);

    // -------- layer 1 --------
    gemm_bt_k256<128, false><<<dim3(mblocks, 2), 256, 0, stream>>>(
        xb, Wt1, h, nullptr, n, FDIM);
    att_coef<<<(n + 3) / 4, 256, 0, stream>>>(h, as1, ad1, als, ald, n);
    gat_gather<<<(n + 3) / 4, 256, 0, stream>>>(
        offs, deg, csr_src, als, ald, h, b1, x2, n);

    // -------- layer 2 --------
    gemm_bt_k256<128, false><<<dim3(mblocks, 2), 256, 0, stream>>>(
        x2, Wt2, h, nullptr, n, FDIM);
    att_coef<<<(n + 3) / 4, 256, 0, stream>>>(h, as2, ad2, als, ald, n);
    gat_gather<<<(n + 3) / 4, 256, 0, stream>>>(
        offs, deg, csr_src, als, ald, h, b2, x2, n);

    // -------- final FC: out[n][64] = x2 @ fcW + fcb (FP32 out) --------
    gemm_bt_k256<64, true><<<dim3(mblocks, 1), 256, 0, stream>>>(
        x2, fcWt, out, fcb, n, 64);
}

// Round 10
// 420.511 us; speedup vs baseline: 1.2695x; 1.2695x over previous
//
#include <hip/hip_runtime.h>
#include <hip/hip_bf16.h>

// ---------------------------------------------------------------------------
// NextTaskGAT: 2-layer GAT (H=4, C=64, F_IN=256) + FC(256->64).
// Pinned: inputs fp32 (bf16-grid), edge_index int32, dict order, OUTPUT FP32.
// R10: gat_gather 4x edge unroll (MLP), two-level parallel CSR scan.
// ---------------------------------------------------------------------------

#define HEADS 4
#define FDIM  256

typedef __attribute__((ext_vector_type(4))) float f32x4;
typedef __attribute__((ext_vector_type(8))) short s16x8;

__device__ __forceinline__ void gload_lds16(const void* g, void* l) {
    __builtin_amdgcn_global_load_lds(
        (__attribute__((address_space(1))) void*)g,
        (__attribute__((address_space(3))) void*)l, 16, 0, 0);
}

__device__ __forceinline__ float b2f(unsigned short u) {
    return __uint_as_float((unsigned)u << 16);
}
__device__ __forceinline__ unsigned short f2b(float f) {
    __hip_bfloat16 b = __float2bfloat16(f);
    return *(unsigned short*)&b;
}

// ---------------------------------------------------------------------------
// Conversions: x fp32 -> bf16; W fp32 [K][N] -> bf16 transposed [N][K].
// ---------------------------------------------------------------------------
__global__ void cvt_x_bf16(const float* __restrict__ in,
                           unsigned short* __restrict__ out, int count) {
    int i = blockIdx.x * 256 + threadIdx.x;
    if (i < count) out[i] = f2b(in[i]);
}

__global__ void cvt_w_t(const float* __restrict__ in,
                        unsigned short* __restrict__ out, int rows, int cols) {
    int i = blockIdx.x * 256 + threadIdx.x;
    if (i >= rows * cols) return;
    int r = i / cols, c = i % cols;
    out[c * rows + r] = f2b(in[i]);
}

// ---------------------------------------------------------------------------
// GEMM: C[M][ncol] = A[M][256](bf16) x Bt[ncol][256]^T(bf16), +fp32 bias.
// BM=128, BK=64, 4 waves 2x2, XOR-swizzled 16B groups, global_load_lds.
// ---------------------------------------------------------------------------
template <int BN, bool F32OUT>
__global__ __launch_bounds__(256, 2)
void gemm_bt_k256(const unsigned short* __restrict__ A,
                  const unsigned short* __restrict__ Bt,
                  void* __restrict__ C,
                  const float* __restrict__ bias,
                  int M, int ncol) {
    constexpr int BM = 128, BK = 64;
    constexpr int NFRAG = BN / 32;
    __shared__ __align__(16) unsigned short lA[BM * BK];
    __shared__ __align__(16) unsigned short lB[BN * BK];

    const int tid  = threadIdx.x;
    const int lane = tid & 63;
    const int wave = tid >> 6;
    const int wm = wave & 1, wn = wave >> 1;
    const int m0 = blockIdx.x * BM;
    const int n0 = blockIdx.y * BN;
    const int quad = lane >> 4, col16 = lane & 15;

    f32x4 acc[4][NFRAG];
#pragma unroll
    for (int i = 0; i < 4; ++i)
#pragma unroll
        for (int j = 0; j < NFRAG; ++j) acc[i][j] = (f32x4){0.f, 0.f, 0.f, 0.f};

#pragma unroll 1
    for (int kt = 0; kt < 4; ++kt) {
        const int k0 = kt * BK;
#pragma unroll
        for (int i = 0; i < 4; ++i) {
            int slot = tid + i * 256;
            int row = slot >> 3, g = slot & 7;
            int gs = g ^ (row & 7);
            int rg = m0 + row; rg = rg < M ? rg : (M - 1);
            gload_lds16(A + (size_t)rg * FDIM + k0 + gs * 8,
                        (char*)lA + (size_t)slot * 16);
        }
#pragma unroll
        for (int i = 0; i < BN * 8 / 256; ++i) {
            int slot = tid + i * 256;
            int row = slot >> 3, g = slot & 7;
            int gs = g ^ (row & 7);
            gload_lds16(Bt + (size_t)(n0 + row) * FDIM + k0 + gs * 8,
                        (char*)lB + (size_t)slot * 16);
        }
        __syncthreads();

#pragma unroll
        for (int kk = 0; kk < 2; ++kk) {
            const int kg = kk * 4 + quad;
            s16x8 af[4], bfr[NFRAG];
#pragma unroll
            for (int i = 0; i < 4; ++i) {
                int row = wm * 64 + i * 16 + col16;
                int g = kg ^ (row & 7);
                af[i] = *(const s16x8*)((const char*)lA + (size_t)(row * 8 + g) * 16);
            }
#pragma unroll
            for (int j = 0; j < NFRAG; ++j) {
                int row = wn * (BN / 2) + j * 16 + col16;
                int g = kg ^ (row & 7);
                bfr[j] = *(const s16x8*)((const char*)lB + (size_t)(row * 8 + g) * 16);
            }
#pragma unroll
            for (int i = 0; i < 4; ++i)
#pragma unroll
                for (int j = 0; j < NFRAG; ++j)
                    acc[i][j] = __builtin_amdgcn_mfma_f32_16x16x32_bf16(
                        af[i], bfr[j], acc[i][j], 0, 0, 0);
        }
        __syncthreads();
    }

#pragma unroll
    for (int i = 0; i < 4; ++i) {
#pragma unroll
        for (int j = 0; j < NFRAG; ++j) {
#pragma unroll
            for (int r = 0; r < 4; ++r) {
                int row = m0 + wm * 64 + i * 16 + quad * 4 + r;
                int col = n0 + wn * (BN / 2) + j * 16 + col16;
                if (row < M) {
                    float v = acc[i][j][r];
                    if (bias) v += bias[col];
                    if constexpr (F32OUT)
                        ((float*)C)[(size_t)row * ncol + col] = v;
                    else
                        ((unsigned short*)C)[(size_t)row * ncol + col] = f2b(v);
                }
            }
        }
    }
}

// ---------------------------------------------------------------------------
// Attention coefficients: one wave per node; h bf16, a-vectors fp32.
// ---------------------------------------------------------------------------
__global__ void att_coef(const unsigned short* __restrict__ h,
                         const float* __restrict__ a_src,
                         const float* __restrict__ a_dst,
                         float* __restrict__ als, float* __restrict__ ald,
                         int n) {
    const int lane = threadIdx.x & 63;
    const int wv = (blockIdx.x * blockDim.x + threadIdx.x) >> 6;
    if (wv >= n) return;
    float4 as = *(const float4*)(a_src + 4 * lane);
    float4 ad = *(const float4*)(a_dst + 4 * lane);

    ushort4 hv = *(const ushort4*)(h + (size_t)wv * FDIM + lane * 4);
    float h0 = b2f(hv.x), h1 = b2f(hv.y), h2 = b2f(hv.z), h3 = b2f(hv.w);
    float vs = h0 * as.x + h1 * as.y + h2 * as.z + h3 * as.w;
    float vd = h0 * ad.x + h1 * ad.y + h2 * ad.z + h3 * ad.w;
#pragma unroll
    for (int off = 1; off < 16; off <<= 1) {
        vs += __shfl_xor(vs, off, 16);
        vd += __shfl_xor(vd, off, 16);
    }
    if ((lane & 15) == 0) {
        als[wv * HEADS + (lane >> 4)] = vs;
        ald[wv * HEADS + (lane >> 4)] = vd;
    }
}

// ---------------------------------------------------------------------------
// CSR build: histogram -> two-level parallel scan -> scatter
// ---------------------------------------------------------------------------
__global__ void deg_count(const int* __restrict__ dst, int* __restrict__ deg,
                          int E, int n) {
    int e = blockIdx.x * 256 + threadIdx.x;
    if (e >= E + n) return;
    int d = (e < E) ? dst[e] : (e - E);
    atomicAdd(&deg[d], 1);
}

// Per-256-block exclusive scan; block total to bsum[b].
__global__ void scan_block(const int* __restrict__ deg, int* __restrict__ excl,
                           int* __restrict__ bsum, int n) {
    __shared__ int wsums[4];
    const int tid = threadIdx.x, lane = tid & 63, wv = tid >> 6;
    const int i = blockIdx.x * 256 + tid;
    int v = (i < n) ? deg[i] : 0;
    int acc = v;
#pragma unroll
    for (int d = 1; d < 64; d <<= 1) {
        int t = __shfl_up(acc, d, 64);
        if (lane >= d) acc += t;
    }
    if (lane == 63) wsums[wv] = acc;
    __syncthreads();
    int wo = 0;
#pragma unroll
    for (int k = 0; k < 4; ++k) wo += (k < wv) ? wsums[k] : 0;
    if (i < n) excl[i] = wo + acc - v;
    if (tid == 255) bsum[blockIdx.x] = wo + acc;
}

// Single-wave exclusive scan of block sums (in place).
__global__ void scan_bsum(int* __restrict__ bsum, int nb) {
    const int lane = threadIdx.x;
    int carry = 0;
    for (int s = 0; s < nb; s += 64) {
        int i = s + lane;
        int v = (i < nb) ? bsum[i] : 0;
        int acc = v;
#pragma unroll
        for (int d = 1; d < 64; d <<= 1) {
            int t = __shfl_up(acc, d, 64);
            if (lane >= d) acc += t;
        }
        if (i < nb) bsum[i] = carry + acc - v;
        carry += __shfl(acc, 63, 64);
    }
}

// Add block offset; also init cursor.
__global__ void add_off(int* __restrict__ excl, const int* __restrict__ bsum,
                        int* __restrict__ cursor, int n) {
    int i = blockIdx.x * 256 + threadIdx.x;
    if (i >= n) return;
    int o = excl[i] + bsum[i >> 8];
    excl[i] = o;
    cursor[i] = o;
}

__global__ void scatter_edges(const int* __restrict__ src,
                              const int* __restrict__ dst,
                              int* __restrict__ cursor,
                              int* __restrict__ csr_src, int E, int n) {
    int e = blockIdx.x * 256 + threadIdx.x;
    if (e >= E + n) return;
    int s, d;
    if (e < E) { s = src[e]; d = dst[e]; } else { s = e - E; d = s; }
    int p = atomicAdd(&cursor[d], 1);
    csr_src[p] = s;
}

// ---------------------------------------------------------------------------
// Fused gather, 4x unrolled edge loop for memory-level parallelism.
// One wave per dst node; lane covers flat channels 4*lane..4*lane+3.
// ---------------------------------------------------------------------------
__global__ void gat_gather(const int* __restrict__ off,
                           const int* __restrict__ deg,
                           const int* __restrict__ csr_src,
                           const float* __restrict__ als,
                           const float* __restrict__ ald,
                           const unsigned short* __restrict__ h,
                           const float* __restrict__ bias,
                           unsigned short* __restrict__ x2, int n) {
    const int lane = threadIdx.x & 63;
    const int d = (blockIdx.x * blockDim.x + threadIdx.x) >> 6;
    if (d >= n) return;
    const int head = lane >> 4;
    const float aldh = ald[4 * d + head];
    const int start = off[d];
    const int end = start + deg[d];

    float a0 = 0.f, a1 = 0.f, a2 = 0.f, a3 = 0.f, den = 0.f;
    int j = start;
    for (; j + 4 <= end; j += 4) {
        // batch the index loads, then all dependent loads, then consume
        int s0 = csr_src[j + 0];
        int s1 = csr_src[j + 1];
        int s2 = csr_src[j + 2];
        int s3 = csr_src[j + 3];
        float e0 = als[4 * s0 + head];
        float e1 = als[4 * s1 + head];
        float e2 = als[4 * s2 + head];
        float e3 = als[4 * s3 + head];
        ushort4 hv0 = *(const ushort4*)(h + (size_t)s0 * FDIM + lane * 4);
        ushort4 hv1 = *(const ushort4*)(h + (size_t)s1 * FDIM + lane * 4);
        ushort4 hv2 = *(const ushort4*)(h + (size_t)s2 * FDIM + lane * 4);
        ushort4 hv3 = *(const ushort4*)(h + (size_t)s3 * FDIM + lane * 4);
        e0 += aldh; e0 = e0 > 0.f ? e0 : 0.2f * e0;
        e1 += aldh; e1 = e1 > 0.f ? e1 : 0.2f * e1;
        e2 += aldh; e2 = e2 > 0.f ? e2 : 0.2f * e2;
        e3 += aldh; e3 = e3 > 0.f ? e3 : 0.2f * e3;
        float w0 = __expf(e0), w1 = __expf(e1), w2 = __expf(e2), w3 = __expf(e3);
        den += w0 + w1 + w2 + w3;
        a0 += w0 * b2f(hv0.x) + w1 * b2f(hv1.x) + w2 * b2f(hv2.x) + w3 * b2f(hv3.x);
        a1 += w0 * b2f(hv0.y) + w1 * b2f(hv1.y) + w2 * b2f(hv2.y) + w3 * b2f(hv3.y);
        a2 += w0 * b2f(hv0.z) + w1 * b2f(hv1.z) + w2 * b2f(hv2.z) + w3 * b2f(hv3.z);
        a3 += w0 * b2f(hv0.w) + w1 * b2f(hv1.w) + w2 * b2f(hv2.w) + w3 * b2f(hv3.w);
    }
    for (; j < end; ++j) {
        int s = csr_src[j];
        float e = als[4 * s + head] + aldh;
        e = e > 0.f ? e : 0.2f * e;
        float w = __expf(e);
        ushort4 hv = *(const ushort4*)(h + (size_t)s * FDIM + lane * 4);
        den += w;
        a0 += w * b2f(hv.x);
        a1 += w * b2f(hv.y);
        a2 += w * b2f(hv.z);
        a3 += w * b2f(hv.w);
    }
    const float inv = 1.0f / den;
    const int c = lane * 4;
    float v0 = a0 * inv + bias[c + 0];
    float v1 = a1 * inv + bias[c + 1];
    float v2 = a2 * inv + bias[c + 2];
    float v3 = a3 * inv + bias[c + 3];
    v0 = v0 > 0.f ? v0 : expm1f(v0);
    v1 = v1 > 0.f ? v1 : expm1f(v1);
    v2 = v2 > 0.f ? v2 : expm1f(v2);
    v3 = v3 > 0.f ? v3 : expm1f(v3);
    ushort4 o;
    o.x = f2b(v0); o.y = f2b(v1); o.z = f2b(v2); o.w = f2b(v3);
    *(ushort4*)(x2 + (size_t)d * FDIM + c) = o;
}

// ---------------------------------------------------------------------------
extern "C" void kernel_launch(void* const* d_in, const int* in_sizes, int n_in,
                              void* d_out, int out_size, void* d_ws, size_t ws_size,
                              hipStream_t stream) {
    const float* x   = (const float*)d_in[0];
    const int*   ei  = (const int*)d_in[1];
    const float* W1  = (const float*)d_in[3];
    const float* as1 = (const float*)d_in[4];
    const float* ad1 = (const float*)d_in[5];
    const float* b1  = (const float*)d_in[6];
    const float* W2  = (const float*)d_in[7];
    const float* as2 = (const float*)d_in[8];
    const float* ad2 = (const float*)d_in[9];
    const float* b2  = (const float*)d_in[10];
    const float* fcW = (const float*)d_in[11];
    const float* fcb = (const float*)d_in[12];
    float* out = (float*)d_out;

    const int n = in_sizes[0] / FDIM;   // 50000
    const int E = in_sizes[1] / 2;      // 800000
    const int Etot = E + n;
    const int* srcp = ei;
    const int* dstp = ei + E;
    const int nb = (n + 255) / 256;     // scan blocks

    // -------- workspace carve (256B aligned), ~57 MB --------
    char* ws = (char*)d_ws;
    size_t off_b = 0;
    auto carve = [&](size_t bytes) -> char* {
        char* p = ws + off_b;
        off_b += (bytes + 255) & ~(size_t)255;
        return p;
    };
    unsigned short* xb = (unsigned short*)carve((size_t)n * FDIM * 2);  // also x2
    unsigned short* h  = (unsigned short*)carve((size_t)n * FDIM * 2);
    float* als  = (float*)carve((size_t)n * HEADS * 4);
    float* ald  = (float*)carve((size_t)n * HEADS * 4);
    int* deg    = (int*)carve((size_t)n * 4);
    int* offs   = (int*)carve((size_t)(n + 1) * 4);
    int* cursor = (int*)carve((size_t)n * 4);
    int* bsum   = (int*)carve((size_t)nb * 4);
    int* csr_src = (int*)carve((size_t)Etot * 4);
    unsigned short* Wt1  = (unsigned short*)carve(FDIM * FDIM * 2);
    unsigned short* Wt2  = (unsigned short*)carve(FDIM * FDIM * 2);
    unsigned short* fcWt = (unsigned short*)carve(64 * FDIM * 2);
    unsigned short* x2 = xb;   // alias: xb dead after layer-1 GEMM

    const int mblocks = (n + 127) / 128;

    // -------- conversions (inputs on bf16 grid -> lossless) --------
    cvt_x_bf16<<<((size_t)n * FDIM + 255) / 256, 256, 0, stream>>>(x, xb, n * FDIM);
    cvt_w_t<<<(FDIM * FDIM + 255) / 256, 256, 0, stream>>>(W1, Wt1, FDIM, FDIM);
    cvt_w_t<<<(FDIM * FDIM + 255) / 256, 256, 0, stream>>>(W2, Wt2, FDIM, FDIM);
    cvt_w_t<<<(FDIM * 64 + 255) / 256, 256, 0, stream>>>(fcW, fcWt, FDIM, 64);

    // -------- CSR build --------
    (void)hipMemsetAsync(deg, 0, (size_t)n * 4, stream);
    deg_count<<<(Etot + 255) / 256, 256, 0, stream>>>(dstp, deg, E, n);
    scan_block<<<nb, 256, 0, stream>>>(deg, offs, bsum, n);
    scan_bsum<<<1, 64, 0, stream>>>(bsum, nb);
    add_off<<<nb, 256, 0, stream>>>(offs, bsum, cursor, n);
    scatter_edges<<<(Etot + 255) / 256, 256, 0, stream>>>(
        srcp, dstp, cursor, csr_src, E, n);

    // -------- layer 1 --------
    gemm_bt_k256<128, false><<<dim3(mblocks, 2), 256, 0, stream>>>(
        xb, Wt1, h, nullptr, n, FDIM);
    att_coef<<<(n + 3) / 4, 256, 0, stream>>>(h, as1, ad1, als, ald, n);
    gat_gather<<<(n + 3) / 4, 256, 0, stream>>>(
        offs, deg, csr_src, als, ald, h, b1, x2, n);

    // -------- layer 2 --------
    gemm_bt_k256<128, false><<<dim3(mblocks, 2), 256, 0, stream>>>(
        x2, Wt2, h, nullptr, n, FDIM);
    att_coef<<<(n + 3) / 4, 256, 0, stream>>>(h, as2, ad2, als, ald, n);
    gat_gather<<<(n + 3) / 4, 256, 0, stream>>>(
        offs, deg, csr_src, als, ald, h, b2, x2, n);

    // -------- final FC: out[n][64] = x2 @ fcW + fcb (FP32 out) --------
    gemm_bt_k256<64, true><<<dim3(mblocks, 1), 256, 0, stream>>>(
        x2, fcWt, out, fcb, n, 64);
}

// Round 11
// 403.848 us; speedup vs baseline: 1.3218x; 1.0413x over previous
//
#include <hip/hip_runtime.h>
#include <hip/hip_bf16.h>

// ---------------------------------------------------------------------------
// NextTaskGAT: 2-layer GAT (H=4, C=64, F_IN=256) + FC(256->64).
// Pinned: inputs fp32 (bf16-grid), edge_index int32, dict order, OUTPUT FP32.
// R11: 17->9 dispatches (fused converts, 1-pass CSR scan), att_coef fused
// into GEMM epilogue (block-local, atomic-free), gather unroll x8.
// ---------------------------------------------------------------------------

#define HEADS 4
#define FDIM  256

typedef __attribute__((ext_vector_type(4))) float f32x4;
typedef __attribute__((ext_vector_type(8))) short s16x8;

__device__ __forceinline__ void gload_lds16(const void* g, void* l) {
    __builtin_amdgcn_global_load_lds(
        (__attribute__((address_space(1))) void*)g,
        (__attribute__((address_space(3))) void*)l, 16, 0, 0);
}

__device__ __forceinline__ float b2f(unsigned short u) {
    return __uint_as_float((unsigned)u << 16);
}
__device__ __forceinline__ unsigned short f2b(float f) {
    __hip_bfloat16 b = __float2bfloat16(f);
    return *(unsigned short*)&b;
}

// ---------------------------------------------------------------------------
// Fused conversions: x->bf16 | W1^T | W2^T | fcW^T -> bf16 | zero deg.
// ---------------------------------------------------------------------------
__global__ void cvt_all(const float* __restrict__ x, unsigned short* __restrict__ xb,
                        const float* __restrict__ W1, unsigned short* __restrict__ Wt1,
                        const float* __restrict__ W2, unsigned short* __restrict__ Wt2,
                        const float* __restrict__ fcW, unsigned short* __restrict__ fcWt,
                        int* __restrict__ deg, int nx, int n) {
    int i = blockIdx.x * 256 + threadIdx.x;
    if (i < nx) { xb[i] = f2b(x[i]); return; }
    i -= nx;
    if (i < FDIM * FDIM) {                 // W1: [256][256] -> [c][r]
        int r = i >> 8, c = i & 255;
        Wt1[c * FDIM + r] = f2b(W1[i]);
        return;
    }
    i -= FDIM * FDIM;
    if (i < FDIM * FDIM) {
        int r = i >> 8, c = i & 255;
        Wt2[c * FDIM + r] = f2b(W2[i]);
        return;
    }
    i -= FDIM * FDIM;
    if (i < FDIM * 64) {                   // fcW: [256][64] -> [c][r]
        int r = i >> 6, c = i & 63;
        fcWt[c * FDIM + r] = f2b(fcW[i]);
        return;
    }
    i -= FDIM * 64;
    if (i < n) deg[i] = 0;
}

// ---------------------------------------------------------------------------
// GEMM: C[M][ncol] = A[M][256](bf16) x Bt[ncol][256]^T(bf16), +fp32 bias.
// BM=128, BK=64, 4 waves 2x2, XOR-swizzled 16B groups, global_load_lds.
// ATT: fused attention-coefficient epilogue. With BN=128 and ygrid=2, the
// 64-col half owned by (blockIdx.y, wn) is exactly head = blockIdx.y*2+wn,
// so als/ald reduce block-locally (shfl over 16 lanes), no atomics.
// ---------------------------------------------------------------------------
template <int BN, bool F32OUT, bool ATT>
__global__ __launch_bounds__(256, 2)
void gemm_bt_k256(const unsigned short* __restrict__ A,
                  const unsigned short* __restrict__ Bt,
                  void* __restrict__ C,
                  const float* __restrict__ bias,
                  const float* __restrict__ a_src,
                  const float* __restrict__ a_dst,
                  float* __restrict__ als,
                  float* __restrict__ ald,
                  int M, int ncol) {
    constexpr int BM = 128, BK = 64;
    constexpr int NFRAG = BN / 32;
    __shared__ __align__(16) unsigned short lA[BM * BK];
    __shared__ __align__(16) unsigned short lB[BN * BK];

    const int tid  = threadIdx.x;
    const int lane = tid & 63;
    const int wave = tid >> 6;
    const int wm = wave & 1, wn = wave >> 1;
    const int m0 = blockIdx.x * BM;
    const int n0 = blockIdx.y * BN;
    const int quad = lane >> 4, col16 = lane & 15;

    f32x4 acc[4][NFRAG];
#pragma unroll
    for (int i = 0; i < 4; ++i)
#pragma unroll
        for (int j = 0; j < NFRAG; ++j) acc[i][j] = (f32x4){0.f, 0.f, 0.f, 0.f};

#pragma unroll 1
    for (int kt = 0; kt < 4; ++kt) {
        const int k0 = kt * BK;
#pragma unroll
        for (int i = 0; i < 4; ++i) {
            int slot = tid + i * 256;
            int row = slot >> 3, g = slot & 7;
            int gs = g ^ (row & 7);
            int rg = m0 + row; rg = rg < M ? rg : (M - 1);
            gload_lds16(A + (size_t)rg * FDIM + k0 + gs * 8,
                        (char*)lA + (size_t)slot * 16);
        }
#pragma unroll
        for (int i = 0; i < BN * 8 / 256; ++i) {
            int slot = tid + i * 256;
            int row = slot >> 3, g = slot & 7;
            int gs = g ^ (row & 7);
            gload_lds16(Bt + (size_t)(n0 + row) * FDIM + k0 + gs * 8,
                        (char*)lB + (size_t)slot * 16);
        }
        __syncthreads();

#pragma unroll
        for (int kk = 0; kk < 2; ++kk) {
            const int kg = kk * 4 + quad;
            s16x8 af[4], bfr[NFRAG];
#pragma unroll
            for (int i = 0; i < 4; ++i) {
                int row = wm * 64 + i * 16 + col16;
                int g = kg ^ (row & 7);
                af[i] = *(const s16x8*)((const char*)lA + (size_t)(row * 8 + g) * 16);
            }
#pragma unroll
            for (int j = 0; j < NFRAG; ++j) {
                int row = wn * (BN / 2) + j * 16 + col16;
                int g = kg ^ (row & 7);
                bfr[j] = *(const s16x8*)((const char*)lB + (size_t)(row * 8 + g) * 16);
            }
#pragma unroll
            for (int i = 0; i < 4; ++i)
#pragma unroll
                for (int j = 0; j < NFRAG; ++j)
                    acc[i][j] = __builtin_amdgcn_mfma_f32_16x16x32_bf16(
                        af[i], bfr[j], acc[i][j], 0, 0, 0);
        }
        __syncthreads();
    }

    // C epilogue: D row = quad*4 + r, col = lane&15 (m89-verified layout)
#pragma unroll
    for (int i = 0; i < 4; ++i) {
#pragma unroll
        for (int j = 0; j < NFRAG; ++j) {
#pragma unroll
            for (int r = 0; r < 4; ++r) {
                int row = m0 + wm * 64 + i * 16 + quad * 4 + r;
                int col = n0 + wn * (BN / 2) + j * 16 + col16;
                if (row < M) {
                    float v = acc[i][j][r];
                    if (bias) v += bias[col];
                    if constexpr (F32OUT)
                        ((float*)C)[(size_t)row * ncol + col] = v;
                    else
                        ((unsigned short*)C)[(size_t)row * ncol + col] = f2b(v);
                }
            }
        }
    }

    if constexpr (ATT) {
        const int head = blockIdx.y * 2 + wn;
        float asv[4], adv[4];
#pragma unroll
        for (int j = 0; j < 4; ++j) {
            int c = head * 64 + j * 16 + col16;
            asv[j] = a_src[c];
            adv[j] = a_dst[c];
        }
#pragma unroll
        for (int i = 0; i < 4; ++i) {
#pragma unroll
            for (int r = 0; r < 4; ++r) {
                float vs = acc[i][0][r] * asv[0] + acc[i][1][r] * asv[1]
                         + acc[i][2][r] * asv[2] + acc[i][3][r] * asv[3];
                float vd = acc[i][0][r] * adv[0] + acc[i][1][r] * adv[1]
                         + acc[i][2][r] * adv[2] + acc[i][3][r] * adv[3];
#pragma unroll
                for (int m = 1; m < 16; m <<= 1) {
                    vs += __shfl_xor(vs, m, 16);
                    vd += __shfl_xor(vd, m, 16);
                }
                int row = m0 + wm * 64 + i * 16 + quad * 4 + r;
                if (col16 == 0 && row < M) {
                    als[row * HEADS + head] = vs;
                    ald[row * HEADS + head] = vd;
                }
            }
        }
    }
}

// ---------------------------------------------------------------------------
// CSR build: histogram -> one-pass scan -> scatter
// ---------------------------------------------------------------------------
__global__ void deg_count(const int* __restrict__ dst, int* __restrict__ deg,
                          int E, int n) {
    int e = blockIdx.x * 256 + threadIdx.x;
    if (e >= E + n) return;
    int d = (e < E) ? dst[e] : (e - E);
    atomicAdd(&deg[d], 1);
}

// One-dispatch scan: each block brute-force sums deg[0 .. b*256) (vectorized,
// ~20 MB total extra reads), then scans its own 256 chunk. No ordering deps.
__global__ void csr_scan(const int* __restrict__ deg, int* __restrict__ offs,
                         int* __restrict__ cursor, int n) {
    __shared__ int red[4];
    __shared__ int wsums[4];
    __shared__ int base_sh;
    const int tid = threadIdx.x, lane = tid & 63, wv = tid >> 6;
    const int start = blockIdx.x * 256;

    // 1) base = sum deg[0..start)
    int base = 0;
    for (int i = tid * 4; i < start; i += 1024) {
        int4 v = *(const int4*)(deg + i);     // start % 256 == 0 -> aligned
        base += v.x + v.y + v.z + v.w;
    }
#pragma unroll
    for (int m = 1; m < 64; m <<= 1) base += __shfl_xor(base, m, 64);
    if (lane == 0) red[wv] = base;
    __syncthreads();
    if (tid == 0) base_sh = red[0] + red[1] + red[2] + red[3];

    // 2) scan own chunk
    const int i = start + tid;
    int v = (i < n) ? deg[i] : 0;
    int acc = v;
#pragma unroll
    for (int d = 1; d < 64; d <<= 1) {
        int t = __shfl_up(acc, d, 64);
        if (lane >= d) acc += t;
    }
    if (lane == 63) wsums[wv] = acc;
    __syncthreads();
    int wo = 0;
#pragma unroll
    for (int k = 0; k < 4; ++k) wo += (k < wv) ? wsums[k] : 0;
    if (i < n) {
        int o = base_sh + wo + acc - v;
        offs[i] = o;
        cursor[i] = o;
    }
}

__global__ void scatter_edges(const int* __restrict__ src,
                              const int* __restrict__ dst,
                              int* __restrict__ cursor,
                              int* __restrict__ csr_src, int E, int n) {
    int e = blockIdx.x * 256 + threadIdx.x;
    if (e >= E + n) return;
    int s, d;
    if (e < E) { s = src[e]; d = dst[e]; } else { s = e - E; d = s; }
    int p = atomicAdd(&cursor[d], 1);
    csr_src[p] = s;
}

// ---------------------------------------------------------------------------
// Fused gather, 8x unrolled edge loop. One wave per dst node.
// ---------------------------------------------------------------------------
__global__ void gat_gather(const int* __restrict__ off,
                           const int* __restrict__ deg,
                           const int* __restrict__ csr_src,
                           const float* __restrict__ als,
                           const float* __restrict__ ald,
                           const unsigned short* __restrict__ h,
                           const float* __restrict__ bias,
                           unsigned short* __restrict__ x2, int n) {
    const int lane = threadIdx.x & 63;
    const int d = (blockIdx.x * blockDim.x + threadIdx.x) >> 6;
    if (d >= n) return;
    const int head = lane >> 4;
    const float aldh = ald[4 * d + head];
    const int start = off[d];
    const int end = start + deg[d];

    float a0 = 0.f, a1 = 0.f, a2 = 0.f, a3 = 0.f, den = 0.f;
    int j = start;
    for (; j + 8 <= end; j += 8) {
        int s[8];
#pragma unroll
        for (int u = 0; u < 8; ++u) s[u] = csr_src[j + u];
        float e[8];
#pragma unroll
        for (int u = 0; u < 8; ++u) e[u] = als[4 * s[u] + head];
        ushort4 hv[8];
#pragma unroll
        for (int u = 0; u < 8; ++u)
            hv[u] = *(const ushort4*)(h + (size_t)s[u] * FDIM + lane * 4);
#pragma unroll
        for (int u = 0; u < 8; ++u) {
            float t = e[u] + aldh;
            t = t > 0.f ? t : 0.2f * t;
            float w = __expf(t);
            den += w;
            a0 += w * b2f(hv[u].x);
            a1 += w * b2f(hv[u].y);
            a2 += w * b2f(hv[u].z);
            a3 += w * b2f(hv[u].w);
        }
    }
    for (; j + 4 <= end; j += 4) {
        int s[4];
#pragma unroll
        for (int u = 0; u < 4; ++u) s[u] = csr_src[j + u];
        float e[4];
#pragma unroll
        for (int u = 0; u < 4; ++u) e[u] = als[4 * s[u] + head];
        ushort4 hv[4];
#pragma unroll
        for (int u = 0; u < 4; ++u)
            hv[u] = *(const ushort4*)(h + (size_t)s[u] * FDIM + lane * 4);
#pragma unroll
        for (int u = 0; u < 4; ++u) {
            float t = e[u] + aldh;
            t = t > 0.f ? t : 0.2f * t;
            float w = __expf(t);
            den += w;
            a0 += w * b2f(hv[u].x);
            a1 += w * b2f(hv[u].y);
            a2 += w * b2f(hv[u].z);
            a3 += w * b2f(hv[u].w);
        }
    }
    for (; j < end; ++j) {
        int s = csr_src[j];
        float e = als[4 * s + head] + aldh;
        e = e > 0.f ? e : 0.2f * e;
        float w = __expf(e);
        ushort4 hv = *(const ushort4*)(h + (size_t)s * FDIM + lane * 4);
        den += w;
        a0 += w * b2f(hv.x);
        a1 += w * b2f(hv.y);
        a2 += w * b2f(hv.z);
        a3 += w * b2f(hv.w);
    }
    const float inv = 1.0f / den;
    const int c = lane * 4;
    float v0 = a0 * inv + bias[c + 0];
    float v1 = a1 * inv + bias[c + 1];
    float v2 = a2 * inv + bias[c + 2];
    float v3 = a3 * inv + bias[c + 3];
    v0 = v0 > 0.f ? v0 : expm1f(v0);
    v1 = v1 > 0.f ? v1 : expm1f(v1);
    v2 = v2 > 0.f ? v2 : expm1f(v2);
    v3 = v3 > 0.f ? v3 : expm1f(v3);
    ushort4 o;
    o.x = f2b(v0); o.y = f2b(v1); o.z = f2b(v2); o.w = f2b(v3);
    *(ushort4*)(x2 + (size_t)d * FDIM + c) = o;
}

// ---------------------------------------------------------------------------
extern "C" void kernel_launch(void* const* d_in, const int* in_sizes, int n_in,
                              void* d_out, int out_size, void* d_ws, size_t ws_size,
                              hipStream_t stream) {
    const float* x   = (const float*)d_in[0];
    const int*   ei  = (const int*)d_in[1];
    const float* W1  = (const float*)d_in[3];
    const float* as1 = (const float*)d_in[4];
    const float* ad1 = (const float*)d_in[5];
    const float* b1  = (const float*)d_in[6];
    const float* W2  = (const float*)d_in[7];
    const float* as2 = (const float*)d_in[8];
    const float* ad2 = (const float*)d_in[9];
    const float* b2  = (const float*)d_in[10];
    const float* fcW = (const float*)d_in[11];
    const float* fcb = (const float*)d_in[12];
    float* out = (float*)d_out;

    const int n = in_sizes[0] / FDIM;   // 50000
    const int E = in_sizes[1] / 2;      // 800000
    const int Etot = E + n;
    const int* srcp = ei;
    const int* dstp = ei + E;
    const int nb = (n + 255) / 256;

    // -------- workspace carve (256B aligned), ~57 MB --------
    char* ws = (char*)d_ws;
    size_t off_b = 0;
    auto carve = [&](size_t bytes) -> char* {
        char* p = ws + off_b;
        off_b += (bytes + 255) & ~(size_t)255;
        return p;
    };
    unsigned short* xb = (unsigned short*)carve((size_t)n * FDIM * 2);  // also x2
    unsigned short* h  = (unsigned short*)carve((size_t)n * FDIM * 2);
    float* als  = (float*)carve((size_t)n * HEADS * 4);
    float* ald  = (float*)carve((size_t)n * HEADS * 4);
    int* deg    = (int*)carve((size_t)n * 4);
    int* offs   = (int*)carve((size_t)(n + 1) * 4);
    int* cursor = (int*)carve((size_t)n * 4);
    int* csr_src = (int*)carve((size_t)Etot * 4);
    unsigned short* Wt1  = (unsigned short*)carve(FDIM * FDIM * 2);
    unsigned short* Wt2  = (unsigned short*)carve(FDIM * FDIM * 2);
    unsigned short* fcWt = (unsigned short*)carve(64 * FDIM * 2);
    unsigned short* x2 = xb;   // alias: xb dead after layer-1 GEMM

    const int mblocks = (n + 127) / 128;
    const int nx = n * FDIM;
    const int cvt_total = nx + 2 * FDIM * FDIM + FDIM * 64 + n;

    // -------- fused conversions + deg zeroing --------
    cvt_all<<<(cvt_total + 255) / 256, 256, 0, stream>>>(
        x, xb, W1, Wt1, W2, Wt2, fcW, fcWt, deg, nx, n);

    // -------- CSR build (3 dispatches) --------
    deg_count<<<(Etot + 255) / 256, 256, 0, stream>>>(dstp, deg, E, n);
    csr_scan<<<nb, 256, 0, stream>>>(deg, offs, cursor, n);
    scatter_edges<<<(Etot + 255) / 256, 256, 0, stream>>>(
        srcp, dstp, cursor, csr_src, E, n);

    // -------- layer 1 (GEMM + fused att coef) --------
    gemm_bt_k256<128, false, true><<<dim3(mblocks, 2), 256, 0, stream>>>(
        xb, Wt1, h, nullptr, as1, ad1, als, ald, n, FDIM);
    gat_gather<<<(n + 3) / 4, 256, 0, stream>>>(
        offs, deg, csr_src, als, ald, h, b1, x2, n);

    // -------- layer 2 --------
    gemm_bt_k256<128, false, true><<<dim3(mblocks, 2), 256, 0, stream>>>(
        x2, Wt2, h, nullptr, as2, ad2, als, ald, n, FDIM);
    gat_gather<<<(n + 3) / 4, 256, 0, stream>>>(
        offs, deg, csr_src, als, ald, h, b2, x2, n);

    // -------- final FC: out[n][64] = x2 @ fcW + fcb (FP32 out) --------
    gemm_bt_k256<64, true, false><<<dim3(mblocks, 1), 256, 0, stream>>>(
        x2, fcWt, out, fcb, nullptr, nullptr, nullptr, nullptr, n, 64);
}